// Round 2
// baseline (1388.172 us; speedup 1.0000x reference)
//
#include <hip/hip_runtime.h>
#include <cstdint>
#include <math.h>

#define F_IN 512
#define HID  16
#define NCLS 40
#define OUT_STRIDE 20

// ---------------- deg / dinv ----------------
__global__ void k_hist(const int* __restrict__ dst, int* __restrict__ deg, int E) {
    int e = blockIdx.x * blockDim.x + threadIdx.x;
    if (e < E) atomicAdd(&deg[dst[e]], 1);
}

__global__ void k_dinv(const int* __restrict__ deg, float* __restrict__ dinv, int n) {
    int i = blockIdx.x * blockDim.x + threadIdx.x;
    if (i < n) dinv[i] = rsqrtf((float)deg[i] + 1.0f);  // +1 = self loop
}

// ---------------- GEMM1: h1s[i][c] = (x[i] . W1[:,c]) * dinv[i] ----------------
#define RPT 8  // rows per thread
__global__ __launch_bounds__(256) void k_gemm1(const float* __restrict__ x,
                                               const float* __restrict__ W1,
                                               const float* __restrict__ dinv,
                                               float* __restrict__ h1s, int n) {
    __shared__ float w[F_IN * HID];  // 32 KB
    int t = threadIdx.x;
    for (int i = t * 4; i < F_IN * HID; i += 256 * 4)
        *(float4*)&w[i] = *(const float4*)&W1[i];
    __syncthreads();

    int c = t & 15;          // column 0..15  (lanes 0-15 share rows -> x broadcast)
    int g = t >> 4;          // row group 0..15
    int row0 = (blockIdx.x * 16 + g) * RPT;

    const float* xp[RPT];
#pragma unroll
    for (int r = 0; r < RPT; r++) {
        int rr = row0 + r;
        if (rr >= n) rr = n - 1;  // clamp; garbage acc, store guarded below
        xp[r] = x + (size_t)rr * F_IN;
    }

    float acc[RPT];
#pragma unroll
    for (int r = 0; r < RPT; r++) acc[r] = 0.f;

    for (int k4 = 0; k4 < F_IN / 4; k4++) {
        float4 xv[RPT];
#pragma unroll
        for (int r = 0; r < RPT; r++) xv[r] = *(const float4*)&xp[r][k4 * 4];
#pragma unroll
        for (int kk = 0; kk < 4; kk++) {
            float wv = w[(k4 * 4 + kk) * HID + c];
#pragma unroll
            for (int r = 0; r < RPT; r++)
                acc[r] = fmaf(((const float*)&xv[r])[kk], wv, acc[r]);
        }
    }

#pragma unroll
    for (int r = 0; r < RPT; r++) {
        int rr = row0 + r;
        if (rr < n) h1s[rr * HID + c] = acc[r] * dinv[rr];
    }
}

// ---------------- layer1 aggregation: XCD-sliced edge-parallel scatter-add ----
// acc[d][c] += h1s[s][c] for each edge (s,d).  Block b only handles dst in
// slice (b&7); blockIdx%8 -> XCD round-robin keeps each acc line's writers on
// one XCD so atomics stay L2-local (no cross-XCD line thrash).
__global__ __launch_bounds__(256) void k_scatter1(const int* __restrict__ esrc,
                                                  const int* __restrict__ edst,
                                                  const float* __restrict__ h1s,
                                                  float* __restrict__ acc,
                                                  int E, int sliceN) {
    int lane16 = threadIdx.x & 15;
    int s = blockIdx.x & 7;
    int lo = s * sliceN, hi = lo + sliceN;
    int g = (blockIdx.x >> 3) * (blockDim.x >> 4) + (threadIdx.x >> 4);
    int stride = (gridDim.x >> 3) * (blockDim.x >> 4);
    for (int e = g; e < E; e += stride) {
        int d = edst[e];                       // broadcast across 16 lanes
        if (d < lo || d >= hi) continue;
        int sr = esrc[e];
        atomicAdd(&acc[d * HID + lane16], h1s[sr * HID + lane16]);
    }
}

// ---------------- z = relu(dinv*(acc + h1s_self) + b1) * dinv ----------------
__global__ void k_z(const float* __restrict__ acc, const float* __restrict__ h1s,
                    const float* __restrict__ dinv, const float* __restrict__ b1,
                    float* __restrict__ z, int n) {
    int i4 = blockIdx.x * blockDim.x + threadIdx.x;  // over n*4 float4s
    if (i4 >= n * 4) return;
    int node = i4 >> 2;
    int c0 = (i4 & 3) * 4;
    float dv = dinv[node];
    float4 a = ((const float4*)acc)[i4];
    float4 h = ((const float4*)h1s)[i4];
    float4 o;
    o.x = fmaxf(dv * (a.x + h.x) + b1[c0 + 0], 0.f) * dv;
    o.y = fmaxf(dv * (a.y + h.y) + b1[c0 + 1], 0.f) * dv;
    o.z = fmaxf(dv * (a.z + h.z) + b1[c0 + 2], 0.f) * dv;
    o.w = fmaxf(dv * (a.w + h.w) + b1[c0 + 3], 0.f) * dv;
    ((float4*)z)[i4] = o;
}

// ---------------- layer2 aggregation: only dst%20==0 nodes ----------------
__global__ __launch_bounds__(256) void k_scatter2(const int* __restrict__ esrc,
                                                  const int* __restrict__ edst,
                                                  const float* __restrict__ z,
                                                  float* __restrict__ acc2, int E) {
    int lane16 = threadIdx.x & 15;
    int g = (blockIdx.x * blockDim.x + threadIdx.x) >> 4;
    int stride = (gridDim.x * blockDim.x) >> 4;
    for (int e = g; e < E; e += stride) {
        int d = edst[e];
        if (d % OUT_STRIDE != 0) continue;
        atomicAdd(&acc2[(d / OUT_STRIDE) * HID + lane16], z[esrc[e] * HID + lane16]);
    }
}

// ---------------- layer2 matvec + log_softmax (selected rows) ----------------
__global__ void k_out2(const float* __restrict__ z, const float* __restrict__ acc2,
                       const float* __restrict__ dinv, const float* __restrict__ W2,
                       const float* __restrict__ b2, float* __restrict__ out, int nOut) {
    int lane = threadIdx.x & 63;
    int wv = (blockIdx.x * blockDim.x + threadIdx.x) >> 6;  // one wave per out row
    if (wv >= nOut) return;
    int node = wv * OUT_STRIDE;
    int c = lane & 15;
    float a = dinv[node] * (acc2[wv * HID + c] + z[node * HID + c]);

    int jj = lane < NCLS ? lane : 0;
    float v = 0.f;
#pragma unroll
    for (int cc = 0; cc < 16; cc++) {
        float ac = __shfl(a, cc);  // lane cc holds column cc
        v = fmaf(ac, W2[cc * NCLS + jj], v);
    }
    v += b2[jj];

    float vm = lane < NCLS ? v : -INFINITY;
    for (int off = 1; off < 64; off <<= 1) vm = fmaxf(vm, __shfl_xor(vm, off));
    float ex = lane < NCLS ? expf(v - vm) : 0.f;
    float se = ex;
    for (int off = 1; off < 64; off <<= 1) se += __shfl_xor(se, off);
    float ls = logf(se);
    if (lane < NCLS) out[wv * NCLS + lane] = v - vm - ls;
}

// ---------------- host launcher ----------------
extern "C" void kernel_launch(void* const* d_in, const int* in_sizes, int n_in,
                              void* d_out, int out_size, void* d_ws, size_t ws_size,
                              hipStream_t stream) {
    const int E = in_sizes[0] / 2;
    const int N = in_sizes[1] / F_IN;
    const int nOut = (N + OUT_STRIDE - 1) / OUT_STRIDE;
    const int sliceN = (N + 7) / 8;

    const int* src = (const int*)d_in[0];
    const int* dst = src + E;
    const float* x  = (const float*)d_in[1];
    const float* W1 = (const float*)d_in[2];
    const float* b1 = (const float*)d_in[3];
    const float* W2 = (const float*)d_in[4];
    const float* b2 = (const float*)d_in[5];
    float* out = (float*)d_out;

    // workspace carve (16B aligned); deg|acc|acc2 contiguous for single memset
    uint8_t* w = (uint8_t*)d_ws;
    size_t off = 0;
    auto carve = [&](size_t bytes) {
        void* p = w + off;
        off += (bytes + 15) & ~(size_t)15;
        return p;
    };
    int*   deg  = (int*)carve((size_t)N * 4);
    float* acc  = (float*)carve((size_t)N * HID * 4);
    float* acc2 = (float*)carve((size_t)nOut * HID * 4);
    size_t zero_bytes = off;  // deg+acc+acc2, all 16B-multiples -> contiguous
    float* dinv = (float*)carve((size_t)N * 4);
    float* h1s  = (float*)carve((size_t)N * HID * 4);
    float* z    = (float*)carve((size_t)N * HID * 4);
    (void)ws_size; (void)n_in; (void)out_size;

    const int nbN = (N + 255) / 256;
    const int nbE = (E + 255) / 256;

    hipMemsetAsync(d_ws, 0, zero_bytes, stream);
    k_hist<<<nbE, 256, 0, stream>>>(dst, deg, E);
    k_dinv<<<nbN, 256, 0, stream>>>(deg, dinv, N);
    k_gemm1<<<(N + 16 * RPT - 1) / (16 * RPT), 256, 0, stream>>>(x, W1, dinv, h1s, N);
    k_scatter1<<<1024, 256, 0, stream>>>(src, dst, h1s, acc, E, sliceN);
    k_z<<<(N * 4 + 255) / 256, 256, 0, stream>>>(acc, h1s, dinv, b1, z, N);
    k_scatter2<<<512, 256, 0, stream>>>(src, dst, z, acc2, E);
    k_out2<<<(nOut * 64 + 255) / 256, 256, 0, stream>>>(z, acc2, dinv, W2, b2, out, nOut);
}

// Round 3
// 516.468 us; speedup vs baseline: 2.6878x; 2.6878x over previous
//
#include <hip/hip_runtime.h>
#include <cstdint>
#include <math.h>

#define F_IN 512
#define HID  16
#define NCLS 40
#define OUT_STRIDE 20

// ---------------- deg / dinv ----------------
__global__ void k_hist(const int* __restrict__ dst, int* __restrict__ deg, int E) {
    int e = blockIdx.x * blockDim.x + threadIdx.x;
    if (e < E) atomicAdd(&deg[dst[e]], 1);
}

__global__ void k_dinv(const int* __restrict__ deg, float* __restrict__ dinv, int n) {
    int i = blockIdx.x * blockDim.x + threadIdx.x;
    if (i < n) dinv[i] = rsqrtf((float)deg[i] + 1.0f);  // +1 = self loop
}

// ---------------- block scan (exclusive prefix over deg) ----------------
__global__ void k_scan_a(const int* __restrict__ deg, int* __restrict__ excl,
                         int* __restrict__ bsum, int n) {
    __shared__ int s[256];
    int t = threadIdx.x;
    int i = blockIdx.x * 256 + t;
    int v = (i < n) ? deg[i] : 0;
    s[t] = v;
    __syncthreads();
    for (int off = 1; off < 256; off <<= 1) {
        int tmp = (t >= off) ? s[t - off] : 0;
        __syncthreads();
        s[t] += tmp;
        __syncthreads();
    }
    if (i < n) excl[i] = s[t] - v;
    if (t == 255) bsum[blockIdx.x] = s[t];
}

__global__ void k_scan_b(const int* __restrict__ bsum, int* __restrict__ boff, int nb) {
    __shared__ int s[512];
    int t = threadIdx.x;
    int v = (t < nb) ? bsum[t] : 0;
    s[t] = v;
    __syncthreads();
    for (int off = 1; off < 512; off <<= 1) {
        int tmp = (t >= off) ? s[t - off] : 0;
        __syncthreads();
        s[t] += tmp;
        __syncthreads();
    }
    if (t < nb) boff[t] = s[t] - v;
}

__global__ void k_scan_c(int* __restrict__ excl, const int* __restrict__ boff,
                         int* __restrict__ fpos, int n, int Etot) {
    int i = blockIdx.x * 256 + threadIdx.x;
    if (i < n) {
        int v = excl[i] + boff[blockIdx.x];
        excl[i] = v;
        fpos[i] = v;
        if (i == n - 1) excl[n] = Etot;
    }
}

// ---------------- CSR fill, XCD-sliced by dst range ----------------
// Block b handles only dst in slice (b&7); blockIdx%8 -> XCD round-robin, so
// each slice's contiguous csr region (~1.6 MB) has all its writers on one XCD:
// lines fill completely in that L2 and write back once (vs 194 MB of partial-
// line evictions in the unsliced version).
__global__ __launch_bounds__(256) void k_fill(const int* __restrict__ src,
                                              const int* __restrict__ dst,
                                              int* __restrict__ fpos,
                                              int* __restrict__ csr,
                                              int E, int sliceN) {
    int s = blockIdx.x & 7;
    int lo = s * sliceN, hi = lo + sliceN;
    int i0 = (blockIdx.x >> 3) * blockDim.x + threadIdx.x;
    int stride = (gridDim.x >> 3) * blockDim.x;
    for (int e = i0; e < E; e += stride) {
        int d = dst[e];
        if (d < lo || d >= hi) continue;
        int p = atomicAdd(&fpos[d], 1);
        csr[p] = src[e];
    }
}

// ---------------- GEMM1: h1s[i][c] = (x[i] . W1[:,c]) * dinv[i] ----------------
#define RPT 8  // rows per thread
__global__ __launch_bounds__(256) void k_gemm1(const float* __restrict__ x,
                                               const float* __restrict__ W1,
                                               const float* __restrict__ dinv,
                                               float* __restrict__ h1s, int n) {
    __shared__ float w[F_IN * HID];  // 32 KB
    int t = threadIdx.x;
    for (int i = t * 4; i < F_IN * HID; i += 256 * 4)
        *(float4*)&w[i] = *(const float4*)&W1[i];
    __syncthreads();

    int c = t & 15;          // column 0..15  (lanes 0-15 share rows -> x broadcast)
    int g = t >> 4;          // row group 0..15
    int row0 = (blockIdx.x * 16 + g) * RPT;

    const float* xp[RPT];
#pragma unroll
    for (int r = 0; r < RPT; r++) {
        int rr = row0 + r;
        if (rr >= n) rr = n - 1;  // clamp; garbage acc, store guarded below
        xp[r] = x + (size_t)rr * F_IN;
    }

    float acc[RPT];
#pragma unroll
    for (int r = 0; r < RPT; r++) acc[r] = 0.f;

    for (int k4 = 0; k4 < F_IN / 4; k4++) {
        float4 xv[RPT];
#pragma unroll
        for (int r = 0; r < RPT; r++) xv[r] = *(const float4*)&xp[r][k4 * 4];
#pragma unroll
        for (int kk = 0; kk < 4; kk++) {
            float wv = w[(k4 * 4 + kk) * HID + c];
#pragma unroll
            for (int r = 0; r < RPT; r++)
                acc[r] = fmaf(((const float*)&xv[r])[kk], wv, acc[r]);
        }
    }

#pragma unroll
    for (int r = 0; r < RPT; r++) {
        int rr = row0 + r;
        if (rr < n) h1s[rr * HID + c] = acc[r] * dinv[rr];
    }
}

// ---------------- layer1 aggregation, wave per node ----------------
// z[d][c] = relu(dinv[d]*(sum_{s->d} h1s[s][c] + h1s[d][c]) + b1[c]) * dinv[d]
// 4 sub-groups of 16 lanes walk the CSR row in parallel (4 gathers in flight),
// then shuffle-reduce across sub-groups.
__global__ __launch_bounds__(256) void k_agg1(const float* __restrict__ h1s,
                                              const int* __restrict__ csr,
                                              const int* __restrict__ roff,
                                              const float* __restrict__ dinv,
                                              const float* __restrict__ b1,
                                              float* __restrict__ z, int n) {
    int lane = threadIdx.x & 63;
    int node = (blockIdx.x * blockDim.x + threadIdx.x) >> 6;  // one wave per node
    if (node >= n) return;
    int c = lane & 15, sub = lane >> 4;
    int s0 = roff[node], s1 = roff[node + 1];
    float sum = 0.f;
    for (int j = s0 + sub; j < s1; j += 4) sum += h1s[csr[j] * HID + c];
    sum += __shfl_xor(sum, 16);
    sum += __shfl_xor(sum, 32);
    sum += h1s[node * HID + c];  // self loop
    float dv = dinv[node];
    float pre = dv * sum + b1[c];
    if (lane < 16) z[node * HID + c] = fmaxf(pre, 0.f) * dv;
}

// ---------------- layer2 (selected rows only) + log_softmax ----------------
// out[r] = log_softmax( dinv[i]*(sum_{s->i} z[s] + z[i]) @ W2 + b2 ),  i = 20r
__global__ void k_out(const float* __restrict__ z, const int* __restrict__ csr,
                      const int* __restrict__ roff, const float* __restrict__ dinv,
                      const float* __restrict__ W2, const float* __restrict__ b2,
                      float* __restrict__ out, int nOut) {
    int lane = threadIdx.x & 63;
    int wv = (blockIdx.x * blockDim.x + threadIdx.x) >> 6;  // one wave per out row
    if (wv >= nOut) return;
    int node = wv * OUT_STRIDE;
    int c = lane & 15, sub = lane >> 4;
    int s0 = roff[node], s1 = roff[node + 1];
    float sum = 0.f;
    for (int j = s0 + sub; j < s1; j += 4) sum += z[csr[j] * HID + c];
    sum += __shfl_xor(sum, 16);
    sum += __shfl_xor(sum, 32);
    sum += z[node * HID + c];  // self loop
    float a = dinv[node] * sum;

    int jj = lane < NCLS ? lane : 0;
    float v = 0.f;
#pragma unroll
    for (int cc = 0; cc < 16; cc++) {
        float ac = __shfl(a, cc);  // lane cc holds column cc (sub==0)
        v = fmaf(ac, W2[cc * NCLS + jj], v);
    }
    v += b2[jj];

    float vm = lane < NCLS ? v : -INFINITY;
    for (int off = 1; off < 64; off <<= 1) vm = fmaxf(vm, __shfl_xor(vm, off));
    float ex = lane < NCLS ? expf(v - vm) : 0.f;
    float se = ex;
    for (int off = 1; off < 64; off <<= 1) se += __shfl_xor(se, off);
    float ls = logf(se);
    if (lane < NCLS) out[wv * NCLS + lane] = v - vm - ls;
}

// ---------------- host launcher ----------------
extern "C" void kernel_launch(void* const* d_in, const int* in_sizes, int n_in,
                              void* d_out, int out_size, void* d_ws, size_t ws_size,
                              hipStream_t stream) {
    const int E = in_sizes[0] / 2;
    const int N = in_sizes[1] / F_IN;
    const int nOut = (N + OUT_STRIDE - 1) / OUT_STRIDE;
    const int sliceN = (N + 7) / 8;

    const int* src = (const int*)d_in[0];
    const int* dst = src + E;
    const float* x  = (const float*)d_in[1];
    const float* W1 = (const float*)d_in[2];
    const float* b1 = (const float*)d_in[3];
    const float* W2 = (const float*)d_in[4];
    const float* b2 = (const float*)d_in[5];
    float* out = (float*)d_out;

    // workspace carve (16B aligned); deg first so one memset covers it
    uint8_t* w = (uint8_t*)d_ws;
    size_t off = 0;
    auto carve = [&](size_t bytes) {
        void* p = w + off;
        off += (bytes + 15) & ~(size_t)15;
        return p;
    };
    int*   deg  = (int*)carve((size_t)N * 4);
    float* dinv = (float*)carve((size_t)N * 4);
    int*   roff = (int*)carve((size_t)(N + 1) * 4);
    int*   fpos = (int*)carve((size_t)N * 4);
    int*   bsum = (int*)carve(512 * 4);
    int*   boff = (int*)carve(512 * 4);
    int*   csr  = (int*)carve((size_t)E * 4);
    float* h1s  = (float*)carve((size_t)N * HID * 4);
    float* z    = (float*)carve((size_t)N * HID * 4);
    (void)ws_size; (void)n_in; (void)out_size;

    const int nbN = (N + 255) / 256;     // 391 (<=512 required for scan_b)
    const int nbE = (E + 255) / 256;

    hipMemsetAsync(deg, 0, (size_t)N * 4, stream);
    k_hist<<<nbE, 256, 0, stream>>>(dst, deg, E);
    k_dinv<<<nbN, 256, 0, stream>>>(deg, dinv, N);
    k_scan_a<<<nbN, 256, 0, stream>>>(deg, roff, bsum, N);
    k_scan_b<<<1, 512, 0, stream>>>(bsum, boff, nbN);
    k_scan_c<<<nbN, 256, 0, stream>>>(roff, boff, fpos, N, E);
    k_fill<<<1024, 256, 0, stream>>>(src, dst, fpos, csr, E, sliceN);
    k_gemm1<<<(N + 16 * RPT - 1) / (16 * RPT), 256, 0, stream>>>(x, W1, dinv, h1s, N);
    k_agg1<<<(N * 64 + 255) / 256, 256, 0, stream>>>(h1s, csr, roff, dinv, b1, z, N);
    k_out<<<(nOut * 64 + 255) / 256, 256, 0, stream>>>(z, csr, roff, dinv, W2, b2, out, nOut);
}

// Round 4
// 443.670 us; speedup vs baseline: 3.1288x; 1.1641x over previous
//
#include <hip/hip_runtime.h>
#include <cstdint>
#include <math.h>

#define F_IN 512
#define HID  16
#define NCLS 40
#define OUT_STRIDE 20

// ---------------- deg / dinv ----------------
__global__ void k_hist(const int* __restrict__ dst, int* __restrict__ deg, int E) {
    int e = blockIdx.x * blockDim.x + threadIdx.x;
    if (e < E) atomicAdd(&deg[dst[e]], 1);
}

__global__ void k_dinv(const int* __restrict__ deg, float* __restrict__ dinv, int n) {
    int i = blockIdx.x * blockDim.x + threadIdx.x;
    if (i < n) dinv[i] = rsqrtf((float)deg[i] + 1.0f);  // +1 = self loop
}

// ---------------- block scan (exclusive prefix over deg) ----------------
__global__ void k_scan_a(const int* __restrict__ deg, int* __restrict__ excl,
                         int* __restrict__ bsum, int n) {
    __shared__ int s[256];
    int t = threadIdx.x;
    int i = blockIdx.x * 256 + t;
    int v = (i < n) ? deg[i] : 0;
    s[t] = v;
    __syncthreads();
    for (int off = 1; off < 256; off <<= 1) {
        int tmp = (t >= off) ? s[t - off] : 0;
        __syncthreads();
        s[t] += tmp;
        __syncthreads();
    }
    if (i < n) excl[i] = s[t] - v;
    if (t == 255) bsum[blockIdx.x] = s[t];
}

__global__ void k_scan_b(const int* __restrict__ bsum, int* __restrict__ boff, int nb) {
    __shared__ int s[512];
    int t = threadIdx.x;
    int v = (t < nb) ? bsum[t] : 0;
    s[t] = v;
    __syncthreads();
    for (int off = 1; off < 512; off <<= 1) {
        int tmp = (t >= off) ? s[t - off] : 0;
        __syncthreads();
        s[t] += tmp;
        __syncthreads();
    }
    if (t < nb) boff[t] = s[t] - v;
}

__global__ void k_scan_c(int* __restrict__ excl, const int* __restrict__ boff,
                         int* __restrict__ fpos, int n, int Etot) {
    int i = blockIdx.x * 256 + threadIdx.x;
    if (i < n) {
        int v = excl[i] + boff[blockIdx.x];
        excl[i] = v;
        fpos[i] = v;
        if (i == n - 1) excl[n] = Etot;
    }
}

// ---------------- CSR fill, XCD-sliced by dst range ----------------
__global__ __launch_bounds__(256) void k_fill(const int* __restrict__ src,
                                              const int* __restrict__ dst,
                                              int* __restrict__ fpos,
                                              int* __restrict__ csr,
                                              int E, int sliceN) {
    int s = blockIdx.x & 7;
    int lo = s * sliceN, hi = lo + sliceN;
    int i0 = (blockIdx.x >> 3) * blockDim.x + threadIdx.x;
    int stride = (gridDim.x >> 3) * blockDim.x;
    for (int e = i0; e < E; e += stride) {
        int d = dst[e];
        if (d < lo || d >= hi) continue;
        int p = atomicAdd(&fpos[d], 1);
        csr[p] = src[e];
    }
}

// ---------------- GEMM1: h1s[i][c] = (x[i] . W1[:,c]) * dinv[i] ----------------
// Block = 4 waves, 64-row tile. lane = row (x loads: 16B/lane unique, 1KB/instr),
// wave = K-chunk of 128 (K-split inside block). W read from LDS at wave-uniform
// address -> ds_read_b128 broadcast, conflict-free. Epilogue: waves 1-3 dump
// partials to LDS, wave 0 reduces + scales by dinv + stores contiguous.
#define KS  4
#define KCH (F_IN / KS)  // 128
__global__ __launch_bounds__(256) void k_gemm1(const float* __restrict__ x,
                                               const float* __restrict__ W1,
                                               const float* __restrict__ dinv,
                                               float* __restrict__ h1s, int n) {
    __shared__ float wlds[F_IN * HID];      // 32 KB, [k][c] as in W1
    __shared__ float red[3 * 64 * HID];     // 12 KB partials from waves 1-3
    int t = threadIdx.x;
    int wid = t >> 6;       // wave id = K-chunk id
    int lane = t & 63;      // row within tile

    for (int i = t * 4; i < F_IN * HID; i += 256 * 4)
        *(float4*)&wlds[i] = *(const float4*)&W1[i];
    __syncthreads();

    int row = blockIdx.x * 64 + lane;
    int rclamp = (row < n) ? row : (n - 1);
    const float* xp = x + (size_t)rclamp * F_IN + wid * KCH;
    const float* wp = &wlds[wid * KCH * HID];

    float acc[HID];
#pragma unroll
    for (int c = 0; c < HID; c++) acc[c] = 0.f;

#pragma unroll 8
    for (int k4 = 0; k4 < KCH / 4; k4++) {
        float4 xv = *(const float4*)&xp[k4 * 4];
#pragma unroll
        for (int kk = 0; kk < 4; kk++) {
            float xs = ((const float*)&xv)[kk];
            const float4* wr = (const float4*)&wp[(k4 * 4 + kk) * HID];
#pragma unroll
            for (int cg = 0; cg < 4; cg++) {
                float4 wv = wr[cg];
                acc[cg * 4 + 0] = fmaf(xs, wv.x, acc[cg * 4 + 0]);
                acc[cg * 4 + 1] = fmaf(xs, wv.y, acc[cg * 4 + 1]);
                acc[cg * 4 + 2] = fmaf(xs, wv.z, acc[cg * 4 + 2]);
                acc[cg * 4 + 3] = fmaf(xs, wv.w, acc[cg * 4 + 3]);
            }
        }
    }

    if (wid > 0) {
        float* r = &red[((wid - 1) * 64 + lane) * HID];
#pragma unroll
        for (int cg = 0; cg < 4; cg++)
            *(float4*)&r[cg * 4] = make_float4(acc[cg * 4], acc[cg * 4 + 1],
                                               acc[cg * 4 + 2], acc[cg * 4 + 3]);
    }
    __syncthreads();
    if (wid == 0 && row < n) {
        float dv = dinv[row];
#pragma unroll
        for (int cg = 0; cg < 4; cg++) {
            float4 p0 = *(float4*)&red[(0 * 64 + lane) * HID + cg * 4];
            float4 p1 = *(float4*)&red[(1 * 64 + lane) * HID + cg * 4];
            float4 p2 = *(float4*)&red[(2 * 64 + lane) * HID + cg * 4];
            float4 o;
            o.x = (acc[cg * 4 + 0] + p0.x + p1.x + p2.x) * dv;
            o.y = (acc[cg * 4 + 1] + p0.y + p1.y + p2.y) * dv;
            o.z = (acc[cg * 4 + 2] + p0.z + p1.z + p2.z) * dv;
            o.w = (acc[cg * 4 + 3] + p0.w + p1.w + p2.w) * dv;
            *(float4*)&h1s[(size_t)row * HID + cg * 4] = o;
        }
    }
}

// ---------------- layer1 aggregation, wave per node ----------------
__global__ __launch_bounds__(256) void k_agg1(const float* __restrict__ h1s,
                                              const int* __restrict__ csr,
                                              const int* __restrict__ roff,
                                              const float* __restrict__ dinv,
                                              const float* __restrict__ b1,
                                              float* __restrict__ z, int n) {
    int lane = threadIdx.x & 63;
    int node = (blockIdx.x * blockDim.x + threadIdx.x) >> 6;  // one wave per node
    if (node >= n) return;
    int c = lane & 15, sub = lane >> 4;
    int s0 = roff[node], s1 = roff[node + 1];
    float sum = 0.f;
    for (int j = s0 + sub; j < s1; j += 4) sum += h1s[csr[j] * HID + c];
    sum += __shfl_xor(sum, 16);
    sum += __shfl_xor(sum, 32);
    sum += h1s[node * HID + c];  // self loop
    float dv = dinv[node];
    float pre = dv * sum + b1[c];
    if (lane < 16) z[node * HID + c] = fmaxf(pre, 0.f) * dv;
}

// ---------------- layer2 (selected rows only) + log_softmax ----------------
__global__ void k_out(const float* __restrict__ z, const int* __restrict__ csr,
                      const int* __restrict__ roff, const float* __restrict__ dinv,
                      const float* __restrict__ W2, const float* __restrict__ b2,
                      float* __restrict__ out, int nOut) {
    int lane = threadIdx.x & 63;
    int wv = (blockIdx.x * blockDim.x + threadIdx.x) >> 6;  // one wave per out row
    if (wv >= nOut) return;
    int node = wv * OUT_STRIDE;
    int c = lane & 15, sub = lane >> 4;
    int s0 = roff[node], s1 = roff[node + 1];
    float sum = 0.f;
    for (int j = s0 + sub; j < s1; j += 4) sum += z[csr[j] * HID + c];
    sum += __shfl_xor(sum, 16);
    sum += __shfl_xor(sum, 32);
    sum += z[node * HID + c];  // self loop
    float a = dinv[node] * sum;

    int jj = lane < NCLS ? lane : 0;
    float v = 0.f;
#pragma unroll
    for (int cc = 0; cc < 16; cc++) {
        float ac = __shfl(a, cc);  // lane cc holds column cc (sub==0)
        v = fmaf(ac, W2[cc * NCLS + jj], v);
    }
    v += b2[jj];

    float vm = lane < NCLS ? v : -INFINITY;
    for (int off = 1; off < 64; off <<= 1) vm = fmaxf(vm, __shfl_xor(vm, off));
    float ex = lane < NCLS ? expf(v - vm) : 0.f;
    float se = ex;
    for (int off = 1; off < 64; off <<= 1) se += __shfl_xor(se, off);
    float ls = logf(se);
    if (lane < NCLS) out[wv * NCLS + lane] = v - vm - ls;
}

// ---------------- host launcher ----------------
extern "C" void kernel_launch(void* const* d_in, const int* in_sizes, int n_in,
                              void* d_out, int out_size, void* d_ws, size_t ws_size,
                              hipStream_t stream) {
    const int E = in_sizes[0] / 2;
    const int N = in_sizes[1] / F_IN;
    const int nOut = (N + OUT_STRIDE - 1) / OUT_STRIDE;
    const int sliceN = (N + 7) / 8;

    const int* src = (const int*)d_in[0];
    const int* dst = src + E;
    const float* x  = (const float*)d_in[1];
    const float* W1 = (const float*)d_in[2];
    const float* b1 = (const float*)d_in[3];
    const float* W2 = (const float*)d_in[4];
    const float* b2 = (const float*)d_in[5];
    float* out = (float*)d_out;

    uint8_t* w = (uint8_t*)d_ws;
    size_t off = 0;
    auto carve = [&](size_t bytes) {
        void* p = w + off;
        off += (bytes + 15) & ~(size_t)15;
        return p;
    };
    int*   deg  = (int*)carve((size_t)N * 4);
    float* dinv = (float*)carve((size_t)N * 4);
    int*   roff = (int*)carve((size_t)(N + 1) * 4);
    int*   fpos = (int*)carve((size_t)N * 4);
    int*   bsum = (int*)carve(512 * 4);
    int*   boff = (int*)carve(512 * 4);
    int*   csr  = (int*)carve((size_t)E * 4);
    float* h1s  = (float*)carve((size_t)N * HID * 4);
    float* z    = (float*)carve((size_t)N * HID * 4);
    (void)ws_size; (void)n_in; (void)out_size;

    const int nbN = (N + 255) / 256;     // 391 (<=512 required for scan_b)
    const int nbE = (E + 255) / 256;

    hipMemsetAsync(deg, 0, (size_t)N * 4, stream);
    k_hist<<<nbE, 256, 0, stream>>>(dst, deg, E);
    k_dinv<<<nbN, 256, 0, stream>>>(deg, dinv, N);
    k_scan_a<<<nbN, 256, 0, stream>>>(deg, roff, bsum, N);
    k_scan_b<<<1, 512, 0, stream>>>(bsum, boff, nbN);
    k_scan_c<<<nbN, 256, 0, stream>>>(roff, boff, fpos, N, E);
    k_fill<<<1024, 256, 0, stream>>>(src, dst, fpos, csr, E, sliceN);
    k_gemm1<<<(N + 63) / 64, 256, 0, stream>>>(x, W1, dinv, h1s, N);
    k_agg1<<<(N * 64 + 255) / 256, 256, 0, stream>>>(h1s, csr, roff, dinv, b1, z, N);
    k_out<<<(nOut * 64 + 255) / 256, 256, 0, stream>>>(z, csr, roff, dinv, W2, b2, out, nOut);
}